// Round 8
// baseline (357.577 us; speedup 1.0000x reference)
//
#include <hip/hip_runtime.h>

// SimpleRNN fused kernel for MI355X (gfx950).
// B=256, T=512, I=64, H=256, O=1, fp32.
//
// History:
// R1: padded LDS half-split (conflicts 1.34e8 -> 0, 608 -> 461 us).
// R2: 4-way k-split/1024thr regressed (LDS-bound structure + AGPR stash).
// R3-R5: register knobs never lifted VGPR_Count above 104.
// R6: in-kernel xw GEMM spilled (WRITE_SIZE 33.8MB), regressed.
// R7: LDS-issue-bound fix: J=4/S=8 multi-j mapping, 320->88 LDS instr/step
//     -> 455->319 us, VALUBusy 96%. Now VALU-ISSUE-BOUND at ~405
//     instr/thread/step vs ~200 needed: the 160-float weight set can't fit
//     104 arch VGPRs => AGPR-resident, +1 accvgpr_read per weight use.
// R8: make the working set FIT arch registers instead of fighting the RA:
//     1024 threads, J=4, S=16 -> 80 weight floats/thread (64 wh + 16 wi),
//     hard 128-reg/wave cap (16 waves must co-reside) leaves room => no
//     AGPR stash. FMA halves to 80/thread; emitted as 40 v_pk_fma_f32 via
//     f32x2 ext-vectors. Reduce across 16 k-seg lanes: xor1/xor2 via DPP
//     quad_perm (0xB1/0x4E), xor8 via DPP row_ror:8 (0x128) -- VALU-side;
//     only xor4 uses ds_swizzle (0x101F). h LDS slot(k)=k+4*(k>>4):
//     8 disjoint bank groups (s and s+8 alias -> benign 2-row).

#define RNN_B 256
#define RNN_T 512
#define RNN_I 64
#define RNN_H 256
#define TILE_T 64
#define N_TILES (RNN_T / TILE_T)

typedef float f32x2 __attribute__((ext_vector_type(2)));

template <int CTRL>
__device__ __forceinline__ float dppf(float v) {
    return __builtin_bit_cast(float,
        __builtin_amdgcn_update_dpp(0, __builtin_bit_cast(int, v),
                                    CTRL, 0xF, 0xF, true));
}
__device__ __forceinline__ float swz_xor4(float v) {
    return __builtin_bit_cast(float,
        __builtin_amdgcn_ds_swizzle(__builtin_bit_cast(int, v), 0x101F));
}

__global__
__attribute__((amdgpu_flat_work_group_size(1024, 1024), amdgpu_waves_per_eu(4, 4)))
void rnn_fused_kernel(const float* __restrict__ x,     // [B,T,I]
                      const float* __restrict__ W_ih,  // [H,I]
                      const float* __restrict__ W_hh,  // [H,H]
                      const float* __restrict__ b_ih,  // [H]
                      const float* __restrict__ b_hh,  // [H]
                      const float* __restrict__ fc_W,  // [O,H], O=1
                      const float* __restrict__ fc_b,  // [O]
                      float* __restrict__ out)         // [B,O]
{
    const int b   = blockIdx.x;
    const int tid = threadIdx.x;    // 0..1023
    const int w   = tid >> 6;       // wave 0..15
    const int l   = tid & 63;       // lane
    const int g   = l >> 4;         // j-quad within wave, 0..3
    const int s   = l & 15;         // k-segment, 0..15
    const int j0  = w * 16 + g * 4; // first j of this lane's quad

    __shared__ float hbuf[2][320];        // padded h: slot(k) = k + 4*(k>>4)
    __shared__ float xt[TILE_T][RNN_I];   // x tile: 64 timesteps, 16 KB
    __shared__ float red[16];

    // ---- persistent weights: 4 j-rows x 16-k segment (80 floats) ----
    f32x2 wh2[4][8];   // wh2[jj][2c+{0,1}] = W_hh[j0+jj][16s+4c+{0,1 / 2,3}]
    f32x2 wi2[4][2];   // wi2[jj][{0,1}]   = W_ih[j0+jj][4s+{0,1 / 2,3}]
    #pragma unroll
    for (int jj = 0; jj < 4; ++jj) {
        const float4* src = reinterpret_cast<const float4*>(W_hh + (j0 + jj) * RNN_H + 16 * s);
        #pragma unroll
        for (int c = 0; c < 4; ++c) {
            const float4 v = src[c];
            wh2[jj][2 * c + 0] = f32x2{v.x, v.y};
            wh2[jj][2 * c + 1] = f32x2{v.z, v.w};
        }
        const float4 vi = *reinterpret_cast<const float4*>(W_ih + (j0 + jj) * RNN_I + 4 * s);
        wi2[jj][0] = f32x2{vi.x, vi.y};
        wi2[jj][1] = f32x2{vi.z, vi.w};
    }

    // lane finalizes j_fin after the reduce-scatter (R7-verified pattern)
    const int   jjsel = ((s & 1) << 1) | ((s >> 1) & 1);
    const int   j_fin = j0 + jjsel;
    const int   jslot = j_fin + 4 * w;          // slot(j_fin): j_fin>>4 == w
    const float bias2 = b_ih[j_fin] + b_hh[j_fin];
    const float fcw   = fc_W[j_fin];

    // ---- prologue: h0 = 0; prefetch x tile 0 into registers ----
    if (tid < 320) hbuf[0][tid] = 0.0f;
    const float4* xs4 = reinterpret_cast<const float4*>(x + (size_t)b * RNN_T * RNN_I);
    float4 xreg = xs4[tid];   // tile 0: 1024 float4 = 64 x 64 floats

    float hj = 0.0f;  // this lane's h_new[j_fin]

#define RNN_STEP(CUR, NXT, TT)                                                  \
    {                                                                           \
        const float4* hs = reinterpret_cast<const float4*>(hbuf[CUR] + 20 * s); \
        const float4  xv = *reinterpret_cast<const float4*>(&xt[TT][4 * s]);    \
        f32x2 a0 = {0.f, 0.f}, a1 = {0.f, 0.f}, a2 = {0.f, 0.f}, a3 = {0.f, 0.f}; \
        _Pragma("unroll")                                                       \
        for (int c = 0; c < 4; ++c) {                                           \
            const float4 h4 = hs[c];                                            \
            const f32x2 hA = {h4.x, h4.y}, hB = {h4.z, h4.w};                   \
            a0 = __builtin_elementwise_fma(hA, wh2[0][2 * c + 0], a0);          \
            a0 = __builtin_elementwise_fma(hB, wh2[0][2 * c + 1], a0);          \
            a1 = __builtin_elementwise_fma(hA, wh2[1][2 * c + 0], a1);          \
            a1 = __builtin_elementwise_fma(hB, wh2[1][2 * c + 1], a1);          \
            a2 = __builtin_elementwise_fma(hA, wh2[2][2 * c + 0], a2);          \
            a2 = __builtin_elementwise_fma(hB, wh2[2][2 * c + 1], a2);          \
            a3 = __builtin_elementwise_fma(hA, wh2[3][2 * c + 0], a3);          \
            a3 = __builtin_elementwise_fma(hB, wh2[3][2 * c + 1], a3);          \
        }                                                                       \
        {                                                                       \
            const f32x2 xA = {xv.x, xv.y}, xB = {xv.z, xv.w};                   \
            a0 = __builtin_elementwise_fma(xA, wi2[0][0], a0);                  \
            a0 = __builtin_elementwise_fma(xB, wi2[0][1], a0);                  \
            a1 = __builtin_elementwise_fma(xA, wi2[1][0], a1);                  \
            a1 = __builtin_elementwise_fma(xB, wi2[1][1], a1);                  \
            a2 = __builtin_elementwise_fma(xA, wi2[2][0], a2);                  \
            a2 = __builtin_elementwise_fma(xB, wi2[2][1], a2);                  \
            a3 = __builtin_elementwise_fma(xA, wi2[3][0], a3);                  \
            a3 = __builtin_elementwise_fma(xB, wi2[3][1], a3);                  \
        }                                                                       \
        float p0 = a0.x + a0.y, p1 = a1.x + a1.y;                               \
        float p2 = a2.x + a2.y, p3 = a3.x + a3.y;                               \
        /* reduce-scatter across 16 k-seg lanes: xor1,2 (DPP quad_perm), */     \
        /* xor4 (ds_swizzle), xor8 (DPP row_ror:8)                       */     \
        const bool sb0 = (s & 1) != 0;                                          \
        const float g0 = sb0 ? p0 : p2, g1 = sb0 ? p1 : p3;                     \
        const float k0 = sb0 ? p2 : p0, k1 = sb0 ? p3 : p1;                     \
        const float r0 = k0 + dppf<0xB1>(g0);   /* quad_perm [1,0,3,2] */       \
        const float r1 = k1 + dppf<0xB1>(g1);                                   \
        const bool sb1 = (s & 2) != 0;                                          \
        const float g2 = sb1 ? r0 : r1;                                         \
        const float k2 = sb1 ? r1 : r0;                                         \
        float u = k2 + dppf<0x4E>(g2);          /* quad_perm [2,3,0,1] */       \
        u += swz_xor4(u);                                                       \
        u += dppf<0x128>(u);                    /* row_ror:8 == xor8   */       \
        const float z  = u + bias2;                                             \
        const float zc = fminf(fmaxf(z, -10.f), 10.f);                          \
        const float e  = exp2f(zc * 2.8853900817779268f);     /* e^(2z) */      \
        const float hn = (e - 1.f) * __builtin_amdgcn_rcpf(e + 1.f);            \
        hj = hn;                                                                \
        if (s < 4) hbuf[NXT][jslot] = hn;                                       \
        __syncthreads();                                                        \
    }

    for (int tile = 0; tile < N_TILES; ++tile) {
        // stage current x tile (prev barrier guarantees old tile fully read)
        reinterpret_cast<float4*>(xt)[tid] = xreg;
        if (tile + 1 < N_TILES) xreg = xs4[(tile + 1) * 1024 + tid];
        __syncthreads();   // xt (and h0/weights on tile 0) ready

        for (int tt = 0; tt < TILE_T; tt += 2) {
            RNN_STEP(0, 1, tt)
            RNN_STEP(1, 0, tt + 1)
        }
    }
#undef RNN_STEP

    // ---- epilogue: out[b] = sum_j h_T[j]*fc_W[j] + fc_b ----
    float term = (s < 4) ? hj * fcw : 0.0f;   // each j counted exactly once
    #pragma unroll
    for (int d = 1; d < 64; d <<= 1) term += __shfl_xor(term, d, 64);
    if (l == 0) red[w] = term;
    __syncthreads();
    if (tid == 0) {
        float sum = 0.f;
        #pragma unroll
        for (int ww = 0; ww < 16; ++ww) sum += red[ww];
        out[b] = sum + fc_b[0];
    }
}

extern "C" void kernel_launch(void* const* d_in, const int* in_sizes, int n_in,
                              void* d_out, int out_size, void* d_ws, size_t ws_size,
                              hipStream_t stream) {
    const float* x    = (const float*)d_in[0];
    const float* W_ih = (const float*)d_in[1];
    const float* W_hh = (const float*)d_in[2];
    const float* b_ih = (const float*)d_in[3];
    const float* b_hh = (const float*)d_in[4];
    const float* fc_W = (const float*)d_in[5];
    const float* fc_b = (const float*)d_in[6];
    float* out = (float*)d_out;

    rnn_fused_kernel<<<RNN_B, 1024, 0, stream>>>(x, W_ih, W_hh, b_ih, b_hh, fc_W, fc_b, out);
}

// Round 9
// 349.438 us; speedup vs baseline: 1.0233x; 1.0233x over previous
//
#include <hip/hip_runtime.h>

// SimpleRNN fused kernel for MI355X (gfx950).
// B=256, T=512, I=64, H=256, O=1, fp32.
//
// History:
// R1: padded LDS half-split (conflicts 1.34e8 -> 0, 608 -> 461 us).
// R2: 4-way k-split/1024thr regressed.
// R3-R5: register knobs never lifted VGPR_Count above 104.
// R6: in-kernel xw GEMM spilled (WRITE_SIZE 33.8MB), regressed.
// R7: LDS-issue fix (J=4/S=8 multi-j, 320->88 LDS instr/CU/step):
//     455 -> 319 us, VALUBusy 96% => now VALU-ISSUE-bound
//     (~405 instr/thread/step at 2 waves/SIMD).
// R8: big restructure (1024thr, S=16, pk_fma, DPP reduce) regressed:
//     VALUBusy 65%, more exposed chain latency per lockstep barrier.
//     Reverted.
// R9: R7 + ONE change: pack the 160 scalar v_fma_f32 into 80
//     v_pk_fma_f32 (f32x2 ext-vector + __builtin_elementwise_fma).
//     Halves the dominant VALU issue load; mapping, LDS layout,
//     reduce-scatter, occupancy all identical to R7.

#define RNN_B 256
#define RNN_T 512
#define RNN_I 64
#define RNN_H 256
#define TILE_T 32
#define N_TILES (RNN_T / TILE_T)

typedef float f32x2 __attribute__((ext_vector_type(2)));

__global__
__attribute__((amdgpu_flat_work_group_size(512, 512), amdgpu_waves_per_eu(2, 2)))
void rnn_fused_kernel(const float* __restrict__ x,     // [B,T,I]
                      const float* __restrict__ W_ih,  // [H,I]
                      const float* __restrict__ W_hh,  // [H,H]
                      const float* __restrict__ b_ih,  // [H]
                      const float* __restrict__ b_hh,  // [H]
                      const float* __restrict__ fc_W,  // [O,H], O=1
                      const float* __restrict__ fc_b,  // [O]
                      float* __restrict__ out)         // [B,O]
{
    const int b   = blockIdx.x;
    const int tid = threadIdx.x;    // 0..511
    const int w   = tid >> 6;       // wave 0..7
    const int l   = tid & 63;       // lane
    const int g   = l >> 3;         // j-quad within wave, 0..7
    const int s   = l & 7;          // k-segment, 0..7
    const int j0  = w * 32 + g * 4; // first j of this lane's quad

    __shared__ float hbuf[2][288];        // padded h: slot(j) = j + 4*(j>>5)
    __shared__ float xt[TILE_T][RNN_I];   // x tile: 32 timesteps, 8 KB
    __shared__ float red[8];

    // ---- persistent weights: 4 j-rows x 32-k segment, as f32x2 pairs ----
    f32x2 wh2[4][16];  // wh2[jj][2c+{0,1}] = W_hh[j0+jj][32s+4c+{0,1 / 2,3}]
    f32x2 wi2[4][4];   // wi2[jj][...]     = W_ih[j0+jj][8s + ...]
    #pragma unroll
    for (int jj = 0; jj < 4; ++jj) {
        const float4* src = reinterpret_cast<const float4*>(W_hh + (j0 + jj) * RNN_H + 32 * s);
        #pragma unroll
        for (int c = 0; c < 8; ++c) {
            const float4 v = src[c];
            wh2[jj][2 * c + 0] = f32x2{v.x, v.y};
            wh2[jj][2 * c + 1] = f32x2{v.z, v.w};
        }
        const float4* s2 = reinterpret_cast<const float4*>(W_ih + (j0 + jj) * RNN_I + 8 * s);
        #pragma unroll
        for (int c = 0; c < 2; ++c) {
            const float4 v = s2[c];
            wi2[jj][2 * c + 0] = f32x2{v.x, v.y};
            wi2[jj][2 * c + 1] = f32x2{v.z, v.w};
        }
    }

    // lane finalizes j_fin = j0 + jjsel after the reduce-scatter
    const int   jjsel = ((s & 1) << 1) | ((s >> 1) & 1);
    const int   j_fin = j0 + jjsel;
    const int   jslot = j_fin + 4 * w;          // slot(j_fin): j_fin>>5 == w
    const float bias2 = b_ih[j_fin] + b_hh[j_fin];
    const float fcw   = fc_W[j_fin];

    // ---- prologue: h0 = 0; prefetch x tile 0 into registers ----
    if (tid < 288) hbuf[0][tid] = 0.0f;
    const float4* xs = reinterpret_cast<const float4*>(x + (size_t)b * RNN_T * RNN_I);
    float4 xreg = xs[tid];   // tile 0 (512 float4 = 32 x 64 floats)

    float hj = 0.0f;  // this lane's h_new[j_fin]

#define RNN_STEP(CUR, NXT, TT)                                                  \
    {                                                                           \
        const float4* hs = reinterpret_cast<const float4*>(hbuf[CUR]) + 9 * s;  \
        const float4* xp = reinterpret_cast<const float4*>(&xt[TT][0]) + 2 * s; \
        f32x2 a0 = {0.f, 0.f}, a1 = {0.f, 0.f};                                 \
        f32x2 a2 = {0.f, 0.f}, a3 = {0.f, 0.f};                                 \
        _Pragma("unroll")                                                       \
        for (int c = 0; c < 8; ++c) {                                           \
            const float4 h4 = hs[c];  /* 8 addrs, 8 disjoint bank groups */     \
            const f32x2 hA = {h4.x, h4.y}, hB = {h4.z, h4.w};                   \
            a0 = __builtin_elementwise_fma(hA, wh2[0][2 * c + 0], a0);          \
            a0 = __builtin_elementwise_fma(hB, wh2[0][2 * c + 1], a0);          \
            a1 = __builtin_elementwise_fma(hA, wh2[1][2 * c + 0], a1);          \
            a1 = __builtin_elementwise_fma(hB, wh2[1][2 * c + 1], a1);          \
            a2 = __builtin_elementwise_fma(hA, wh2[2][2 * c + 0], a2);          \
            a2 = __builtin_elementwise_fma(hB, wh2[2][2 * c + 1], a2);          \
            a3 = __builtin_elementwise_fma(hA, wh2[3][2 * c + 0], a3);          \
            a3 = __builtin_elementwise_fma(hB, wh2[3][2 * c + 1], a3);          \
        }                                                                       \
        _Pragma("unroll")                                                       \
        for (int c = 0; c < 2; ++c) {                                           \
            const float4 x4 = xp[c];                                            \
            const f32x2 xA = {x4.x, x4.y}, xB = {x4.z, x4.w};                   \
            a0 = __builtin_elementwise_fma(xA, wi2[0][2 * c + 0], a0);          \
            a0 = __builtin_elementwise_fma(xB, wi2[0][2 * c + 1], a0);          \
            a1 = __builtin_elementwise_fma(xA, wi2[1][2 * c + 0], a1);          \
            a1 = __builtin_elementwise_fma(xB, wi2[1][2 * c + 1], a1);          \
            a2 = __builtin_elementwise_fma(xA, wi2[2][2 * c + 0], a2);          \
            a2 = __builtin_elementwise_fma(xB, wi2[2][2 * c + 1], a2);          \
            a3 = __builtin_elementwise_fma(xA, wi2[3][2 * c + 0], a3);          \
            a3 = __builtin_elementwise_fma(xB, wi2[3][2 * c + 1], a3);          \
        }                                                                       \
        float p0 = a0.x + a0.y, p1 = a1.x + a1.y;                               \
        float p2 = a2.x + a2.y, p3 = a3.x + a3.y;                               \
        /* reduce-scatter across the 8 k-seg lanes (xor 1,2,4) */               \
        const bool sb0 = (s & 1) != 0;                                          \
        const float g0 = sb0 ? p0 : p2, g1 = sb0 ? p1 : p3;   /* give away */   \
        const float k0 = sb0 ? p2 : p0, k1 = sb0 ? p3 : p1;   /* keep     */    \
        const float r0 = k0 + __shfl_xor(g0, 1, 64);                            \
        const float r1 = k1 + __shfl_xor(g1, 1, 64);                            \
        const bool sb1 = (s & 2) != 0;                                          \
        const float g2 = sb1 ? r0 : r1;                                         \
        const float k2 = sb1 ? r1 : r0;                                         \
        const float u  = k2 + __shfl_xor(g2, 2, 64);                            \
        const float v  = u + __shfl_xor(u, 4, 64);   /* full 256-k sum */       \
        const float z  = v + bias2;                                             \
        const float zc = fminf(fmaxf(z, -10.f), 10.f);                          \
        const float e  = exp2f(zc * 2.8853900817779268f);     /* e^(2z) */      \
        const float hn = (e - 1.f) * __builtin_amdgcn_rcpf(e + 1.f);            \
        hj = hn;                                                                \
        if (s < 4) hbuf[NXT][jslot] = hn;   /* 32 lanes, 32 consec banks */     \
        __syncthreads();                                                        \
    }

    for (int tile = 0; tile < N_TILES; ++tile) {
        // stage current x tile from the prefetch register (prev barrier
        // guarantees all reads of the old tile are done)
        reinterpret_cast<float4*>(xt)[tid] = xreg;
        if (tile + 1 < N_TILES) xreg = xs[(tile + 1) * 512 + tid];  // hide ~32 steps
        __syncthreads();   // xt (and h0/weights on tile 0) ready

        for (int tt = 0; tt < TILE_T; tt += 2) {
            RNN_STEP(0, 1, tt)
            RNN_STEP(1, 0, tt + 1)
        }
    }
#undef RNN_STEP

    // ---- epilogue: out[b] = sum_j h_T[j]*fc_W[j] + fc_b ----
    float term = (s < 4) ? hj * fcw : 0.0f;   // each j counted once
    #pragma unroll
    for (int d = 1; d < 64; d <<= 1) term += __shfl_xor(term, d, 64);
    if (l == 0) red[w] = term;
    __syncthreads();
    if (tid == 0) {
        float sum = 0.f;
        #pragma unroll
        for (int ww = 0; ww < 8; ++ww) sum += red[ww];
        out[b] = sum + fc_b[0];
    }
}

extern "C" void kernel_launch(void* const* d_in, const int* in_sizes, int n_in,
                              void* d_out, int out_size, void* d_ws, size_t ws_size,
                              hipStream_t stream) {
    const float* x    = (const float*)d_in[0];
    const float* W_ih = (const float*)d_in[1];
    const float* W_hh = (const float*)d_in[2];
    const float* b_ih = (const float*)d_in[3];
    const float* b_hh = (const float*)d_in[4];
    const float* fc_W = (const float*)d_in[5];
    const float* fc_b = (const float*)d_in[6];
    float* out = (float*)d_out;

    rnn_fused_kernel<<<RNN_B, 512, 0, stream>>>(x, W_ih, W_hh, b_ih, b_hh, fc_W, fc_b, out);
}